// Round 10
// baseline (144.664 us; speedup 1.0000x reference)
//
#include <hip/hip_runtime.h>

#define SEQ   200
#define BATCH 1024
#define DIM   300
#define HID   600
#define VOCAB 100000

#define BW    4              // batches per wave (mlp)
#define JCH   12             // j-chunks across blockIdx.y (mlp)
#define JPER  (HID / JCH)    // 50 j per chunk

#define PACKED_BYTES ((size_t)VOCAB * HID * 2)   // 120,000,000
#define HIDDEN_BYTES ((size_t)BATCH * HID * 4)   // 2,457,600

typedef float f32x4 __attribute__((ext_vector_type(4)));

// ---------- bf16 helpers ----------
__device__ __forceinline__ unsigned int f2bf(float f) {
  const unsigned int u = __float_as_uint(f);
  return (u + 0x7FFFu + ((u >> 16) & 1u)) >> 16;   // RNE
}

// ---------- Kernel 0: pack tables as interleave-at-4 bf16 rows -----------
// packed row v = 75 uint4 chunks; chunk c = {lut[v][4c..4c+3],
// slut[v][4c..4c+3]} as 8 bf16. Output uint4 index v*75+c equals the flat
// f32x4 index o of BOTH inputs -> pure flat 3-stream copy: no div, no
// branch, 2x16B nt-read + 1x16B store.
__global__ __launch_bounds__(256) void convert_kernel(
    const f32x4* __restrict__ lut4,
    const f32x4* __restrict__ slut4,
    uint4* __restrict__ packed) {
  const unsigned int N      = (unsigned int)VOCAB * 75u;  // 7.5M
  const unsigned int stride = gridDim.x * 256u;
  for (unsigned int o = blockIdx.x * 256u + threadIdx.x; o < N; o += stride) {
    const f32x4 l = __builtin_nontemporal_load(lut4 + o);
    const f32x4 s = __builtin_nontemporal_load(slut4 + o);
    uint4 r;
    r.x = f2bf(l.x) | (f2bf(l.y) << 16);
    r.y = f2bf(l.z) | (f2bf(l.w) << 16);
    r.z = f2bf(s.x) | (f2bf(s.y) << 16);
    r.w = f2bf(s.z) | (f2bf(s.w) << 16);
    packed[o] = r;
  }
}

// ---------- Kernel 1: dedup + fused bf16 row-gather ----------------------
// One block per column. 3 s-groups x 75 lanes (225 active); slot = one
// 16B uint4 chunk of the 1200B packed row. Unpack: u.x/u.y -> lut floats
// 4c..4c+3, u.z/u.w -> slut floats 4c..4c+3. LDS-combine across groups.
__global__ __launch_bounds__(256) void embed_bf16_kernel(
    const int* __restrict__ tokens,
    const uint4* __restrict__ packed,
    float* __restrict__ hidden) {
  const int b = blockIdx.x;
  const int tid = threadIdx.x;

  __shared__ int   toks[SEQ];
  __shared__ float keep[SEQ];
  __shared__ float accs[3][75][8];   // 7.2 KB

  for (int s = tid; s < SEQ; s += 256) toks[s] = tokens[s * BATCH + b];
  __syncthreads();

  for (int s = tid; s < SEQ; s += 256) {
    const int t = toks[s];
    float m = 1.f;
    for (int p = 0; p < s; ++p) {
      if (toks[p] == t) { m = 0.f; break; }
    }
    keep[s] = m;
  }
  __syncthreads();

  const int grp  = tid / 75;    // 0,1,2 active; tid 225..255 idle
  const int slot = tid % 75;
  if (grp < 3) {
    float acc[8] = {0.f, 0.f, 0.f, 0.f, 0.f, 0.f, 0.f, 0.f};
    const int s0 = grp * 67;
    const int s1 = (grp == 2) ? SEQ : s0 + 67;
#pragma unroll 4
    for (int s = s0; s < s1; ++s) {
      const float m = keep[s];
      const uint4 u = packed[(size_t)toks[s] * 75u + slot];
      acc[0] += m * __uint_as_float(u.x << 16);
      acc[1] += m * __uint_as_float(u.x & 0xFFFF0000u);
      acc[2] += m * __uint_as_float(u.y << 16);
      acc[3] += m * __uint_as_float(u.y & 0xFFFF0000u);
      acc[4] += m * __uint_as_float(u.z << 16);
      acc[5] += m * __uint_as_float(u.z & 0xFFFF0000u);
      acc[6] += m * __uint_as_float(u.w << 16);
      acc[7] += m * __uint_as_float(u.w & 0xFFFF0000u);
    }
#pragma unroll
    for (int q = 0; q < 8; ++q) accs[grp][slot][q] = acc[q];
  }
  __syncthreads();

  if (tid < 75) {
    float4 o0, o1;   // o0 -> lut part (hb+4c), o1 -> slut part (hb+300+4c)
    o0.x = accs[0][tid][0] + accs[1][tid][0] + accs[2][tid][0];
    o0.y = accs[0][tid][1] + accs[1][tid][1] + accs[2][tid][1];
    o0.z = accs[0][tid][2] + accs[1][tid][2] + accs[2][tid][2];
    o0.w = accs[0][tid][3] + accs[1][tid][3] + accs[2][tid][3];
    o1.x = accs[0][tid][4] + accs[1][tid][4] + accs[2][tid][4];
    o1.y = accs[0][tid][5] + accs[1][tid][5] + accs[2][tid][5];
    o1.z = accs[0][tid][6] + accs[1][tid][6] + accs[2][tid][6];
    o1.w = accs[0][tid][7] + accs[1][tid][7] + accs[2][tid][7];
    float* hb = hidden + (size_t)b * HID;
    *(float4*)(hb + 4 * tid)       = o0;
    *(float4*)(hb + DIM + 4 * tid) = o1;
  }
}

// ---------- Kernel 2a: out[b] = b2 ---------------------------------------
__global__ __launch_bounds__(256) void out_init_kernel(
    float* __restrict__ out, const float* __restrict__ b2) {
  const int i = blockIdx.x * 256 + threadIdx.x;
  if (i < BATCH) out[i] = b2[0];
}

// ---------- Kernel 2b: MLP — 4 batches/wave, W1 reused 4x, DPP reduce ----
template <int CTRL>
__device__ __forceinline__ float dpp_add(float x) {
  const int y = __builtin_amdgcn_update_dpp(
      0, __float_as_int(x), CTRL, 0xf, 0xf, true);
  return x + __int_as_float(y);
}

__device__ __forceinline__ float wave_sum(float h) {
  h = dpp_add<0x111>(h);   // row_shr:1
  h = dpp_add<0x112>(h);   // row_shr:2
  h = dpp_add<0x114>(h);   // row_shr:4
  h = dpp_add<0x118>(h);   // row_shr:8
  h = dpp_add<0x142>(h);   // row_bcast:15
  h = dpp_add<0x143>(h);   // row_bcast:31  -> lane 63 holds full sum
  return h;
}

__global__ __launch_bounds__(256) void mlp_kernel(
    const float* __restrict__ hidden,
    const float* __restrict__ W1,
    const float* __restrict__ b1,
    const float* __restrict__ W2,
    float* __restrict__ out) {
  const int wave = threadIdx.x >> 6;
  const int lane = threadIdx.x & 63;
  const int b0   = (blockIdx.x * 4 + wave) * BW;
  const int j0   = blockIdx.y * JPER;

  // preload 4 hidden rows: k = lane + 64*i (600 = 64*9 + 24)
  float a[BW][10];
#pragma unroll
  for (int bb = 0; bb < BW; ++bb) {
    const float* __restrict__ hb = hidden + (size_t)(b0 + bb) * HID;
#pragma unroll
    for (int i = 0; i < 9; ++i) a[bb][i] = hb[lane + 64 * i];
    a[bb][9] = (lane < 24) ? hb[lane + 576] : 0.f;
  }

  float acc[BW] = {0.f, 0.f, 0.f, 0.f};

#pragma unroll 2
  for (int jj = 0; jj < JPER; ++jj) {
    const int j = j0 + jj;
    const float* __restrict__ wr = W1 + (size_t)j * HID;
    float d0 = 0.f, d1 = 0.f, d2 = 0.f, d3 = 0.f;
#pragma unroll
    for (int i = 0; i < 9; ++i) {
      const float w = wr[lane + 64 * i];
      d0 += a[0][i] * w;
      d1 += a[1][i] * w;
      d2 += a[2][i] * w;
      d3 += a[3][i] * w;
    }
    {
      const float w = (lane < 24) ? wr[lane + 576] : 0.f;
      d0 += a[0][9] * w;
      d1 += a[1][9] * w;
      d2 += a[2][9] * w;
      d3 += a[3][9] * w;
    }
    // 4 independent 6-step DPP chains (ILP hides DPP latency)
    d0 = wave_sum(d0); d1 = wave_sum(d1);
    d2 = wave_sum(d2); d3 = wave_sum(d3);
    // branch-free epilogue: only lane 63's acc is ever consumed
    const float b1j = b1[j];
    const float w2j = W2[j];
    acc[0] += fmaxf(d0 + b1j, 0.f) * w2j;
    acc[1] += fmaxf(d1 + b1j, 0.f) * w2j;
    acc[2] += fmaxf(d2 + b1j, 0.f) * w2j;
    acc[3] += fmaxf(d3 + b1j, 0.f) * w2j;
  }

  if (lane == 63) {
#pragma unroll
    for (int bb = 0; bb < BW; ++bb) atomicAdd(&out[b0 + bb], acc[bb]);
  }
}

extern "C" void kernel_launch(void* const* d_in, const int* in_sizes, int n_in,
                              void* d_out, int out_size, void* d_ws, size_t ws_size,
                              hipStream_t stream) {
  const int*   tokens = (const int*)  d_in[0];
  const float* lut    = (const float*)d_in[1];
  const float* slut   = (const float*)d_in[2];
  const float* W1     = (const float*)d_in[3];
  const float* b1     = (const float*)d_in[4];
  const float* W2     = (const float*)d_in[5];
  const float* b2     = (const float*)d_in[6];
  float* out = (float*)d_out;

  uint4* packed = (uint4*)d_ws;
  float* hidden = (float*)((char*)d_ws + PACKED_BYTES);

  out_init_kernel<<<(BATCH + 255) / 256, 256, 0, stream>>>(out, b2);
  convert_kernel<<<2048, 256, 0, stream>>>(
      (const f32x4*)lut, (const f32x4*)slut, packed);
  embed_bf16_kernel<<<BATCH, 256, 0, stream>>>(tokens, packed, hidden);
  mlp_kernel<<<dim3(BATCH / (4 * BW), JCH), 256, 0, stream>>>(
      hidden, W1, b1, W2, out);
}